// Round 12
// baseline (841.556 us; speedup 1.0000x reference)
//
#include <hip/hip_runtime.h>
#include <hip/hip_bf16.h>
#include <stdint.h>

#define DD 128
#define HH 256
#define EPSBN 1e-5f

typedef __attribute__((ext_vector_type(4))) float f32x4;
typedef __attribute__((ext_vector_type(8))) short s16x8;
typedef __attribute__((ext_vector_type(4))) short s16x4;

__device__ __forceinline__ unsigned short f2bf(float f){
  union { __hip_bfloat16 h; unsigned short u; } v;
  v.h = __float2bfloat16(f);
  return v.u;
}
__device__ __forceinline__ float bf2f(unsigned short s){
  union{unsigned u; float f;} v; v.u=((unsigned)s)<<16; return v.f;
}
// XOR swizzle inside a 64-row x 512-byte LDS tile (wide XOR: conflicts 2.08e7 -> ~5e6)
__device__ __forceinline__ int swz(int row, int kb){ return row*512 + (kb ^ ((row&31)<<4)); }

// ---------------- weight transpose (fp32 [k][n] -> bf16 [n][k]) ----------------
__global__ void wt_kernel(const float* __restrict__ W1b, const float* __restrict__ W2b,
                          const float* __restrict__ W1a, const float* __restrict__ W2a,
                          unsigned short* __restrict__ WT1b, unsigned short* __restrict__ WT2b,
                          unsigned short* __restrict__ WT1a, unsigned short* __restrict__ WT2a){
  int idx = blockIdx.x*256 + threadIdx.x;
  if (idx < 65536){ int n=idx>>8, k=idx&255; WT1b[n*256+k]=f2bf(W1b[k*256+n]); }
  else if (idx < 98304){ int t=idx-65536; int n=t>>8, k=t&255; WT2b[n*256+k]=f2bf(W2b[k*128+n]); }
  else if (idx < 163840){ int t=idx-98304; int n=t>>8, k=t&255; WT1a[n*256+k]=f2bf(W1a[k*256+n]); }
  else if (idx < 196608){ int t=idx-163840; int n=t>>8, k=t&255; WT2a[n*256+k]=f2bf(W2a[k*128+n]); }
}

// ---------------- fused: h fp32 -> bf16  +  dst histogram (n8 == E here) ----------------
__global__ void h2bf_hist_kernel(const float* __restrict__ h, unsigned short* __restrict__ hb, int n8,
                                 const int* __restrict__ dst, int* __restrict__ counts, int E){
  int i = blockIdx.x*256 + threadIdx.x;
  if (i < n8){
    f32x4 a = *(const f32x4*)(h + (size_t)i*8);
    f32x4 b = *(const f32x4*)(h + (size_t)i*8 + 4);
    s16x8 p;
    #pragma unroll
    for (int q=0;q<4;q++){ p[q]=(short)f2bf(a[q]); p[4+q]=(short)f2bf(b[q]); }
    *(s16x8*)(hb + (size_t)i*8) = p;
  }
  if (i < E) atomicAdd(&counts[dst[i]], 1);
}

__global__ void scan_kernel(const int* __restrict__ counts, int* __restrict__ offsets,
                            int* __restrict__ cursor, int n){
  __shared__ int wsum[16];
  int tid = threadIdx.x, lane = tid&63, wid = tid>>6;
  int carry = 0;
  int nch = (n + 1023)/1024;
  for (int ch=0; ch<nch; ch++){
    int i = ch*1024 + tid;
    int v = (i<n)? counts[i] : 0;
    int s = v;
    #pragma unroll
    for (int off=1; off<64; off<<=1){ int t = __shfl_up(s, off); if (lane>=off) s += t; }
    if (lane==63) wsum[wid] = s;
    __syncthreads();
    int woff = 0, tot = 0;
    #pragma unroll
    for (int w=0; w<16; w++){ int t = wsum[w]; if (w<wid) woff += t; tot += t; }
    if (i<n){ int excl = carry + woff + s - v; offsets[i]=excl; cursor[i]=excl; }
    carry += tot;
    __syncthreads();
  }
  if (tid==0) offsets[n] = carry;
}

// fill also dereferences src[i] once so the gather loop has NO src[eid] chase
__global__ void fill_kernel(const int* __restrict__ dst, const int* __restrict__ srcv,
                            int* __restrict__ cursor,
                            int* __restrict__ eids, int* __restrict__ esrc, int E){
  int i = blockIdx.x*256 + threadIdx.x;
  if (i < E){
    int slot = atomicAdd(&cursor[dst[i]], 1);
    eids[slot] = i;
    esrc[slot] = srcv[i];
  }
}

// ===== shared 512-thr GEMM1 core: x[64x256](LDS) @ WT[256x256](regs) + b, BN stats, y bf16 out =====
__device__ __forceinline__ void gemm1_core(char* xt, const s16x8 (&Bf)[8][2],
                                           float bias0, float bias1,
                                           unsigned short* __restrict__ yout,
                                           float* __restrict__ stats,
                                           int base, int nrows)
{
  const int tid = threadIdx.x;
  const int l = tid&63, w = tid>>6, lr = l&15, lg = l>>4;
  const int nb = w*32;
  f32x4 acc[4][2];
  #pragma unroll
  for (int mt=0;mt<4;mt++)
    #pragma unroll
    for (int nt=0;nt<2;nt++) acc[mt][nt] = (f32x4){0.f,0.f,0.f,0.f};
  #pragma unroll
  for (int kc=0;kc<8;kc++){
    s16x8 af[4];
    #pragma unroll
    for (int mt=0;mt<4;mt++)
      af[mt] = *(const s16x8*)(xt + swz(mt*16 + lr, kc*64 + lg*16));
    #pragma unroll
    for (int nt=0;nt<2;nt++)
      #pragma unroll
      for (int mt=0;mt<4;mt++)
        acc[mt][nt] = __builtin_amdgcn_mfma_f32_16x16x32_bf16(af[mt], Bf[kc][nt], acc[mt][nt], 0,0,0);
  }
  float st1a=0.f, st1b=0.f, st2a=0.f, st2b=0.f;
  #pragma unroll
  for (int mt=0;mt<4;mt++)
    #pragma unroll
    for (int q=0;q<4;q++){
      float m = (base + mt*16 + lg*4 + q < nrows) ? 1.0f : 0.0f;
      float v0 = (acc[mt][0][q] + bias0)*m;
      float v1 = (acc[mt][1][q] + bias1)*m;
      st1a += v0; st2a += v0*v0;
      st1b += v1; st2b += v1*v1;
    }
  __syncthreads();
  #pragma unroll
  for (int mt=0;mt<4;mt++)
    #pragma unroll
    for (int q=0;q<4;q++){
      *(unsigned short*)(xt + (mt*16 + lg*4 + q)*512 + (nb + lr)*2)      = f2bf(acc[mt][0][q] + bias0);
      *(unsigned short*)(xt + (mt*16 + lg*4 + q)*512 + (nb + 16 + lr)*2) = f2bf(acc[mt][1][q] + bias1);
    }
  __syncthreads();
  #pragma unroll
  for (int it=0;it<4;it++){
    int off = it*8192 + tid*16;
    int row = off >> 9;
    if (base + row < nrows)
      *(s16x8*)((char*)yout + (size_t)base*512 + off) = *(const s16x8*)(xt + off);
  }
  {
    int rep = blockIdx.x & 63;
    float s;
    s = st1a; s += __shfl_xor(s,16); s += __shfl_xor(s,32);
    if (l < 16) atomicAdd(&stats[rep*512 + nb + lr], s);
    s = st2a; s += __shfl_xor(s,16); s += __shfl_xor(s,32);
    if (l < 16) atomicAdd(&stats[rep*512 + 256 + nb + lr], s);
    s = st1b; s += __shfl_xor(s,16); s += __shfl_xor(s,32);
    if (l < 16) atomicAdd(&stats[rep*512 + nb + 16 + lr], s);
    s = st2b; s += __shfl_xor(s,16); s += __shfl_xor(s,32);
    if (l < 16) atomicAdd(&stats[rep*512 + 256 + nb + 16 + lr], s);
  }
}

// ================= edge MLP stage 1: one 64-row tile per block (R5/R10-proven) =================
__global__ __launch_bounds__(512, 4) void edge_mlp1(
    const unsigned short* __restrict__ hb, const float* __restrict__ e,
    const int* __restrict__ src, const int* __restrict__ dstv,
    const unsigned short* __restrict__ WT1, const float* __restrict__ b1,
    unsigned short* __restrict__ yout, float* __restrict__ stats, int E)
{
  __shared__ alignas(16) char xt[32768];
  const int tid = threadIdx.x;
  const int l = tid&63, w = tid>>6, lr = l&15, lg = l>>4;
  const int nb = w*32;
  const int base = blockIdx.x*64;   // E multiple of 64 -> no row guards

  // ---- stage e-half (cols 128..255): coalesced ----
  {
    const int cb = tid&31, r0 = tid>>5;
    #pragma unroll
    for (int k=0;k<4;k++){
      int r = r0 + k*16;
      f32x4 v = *(const f32x4*)(e + (size_t)(base+r)*DD + cb*4);
      s16x4 p;
      #pragma unroll
      for (int q=0;q<4;q++) p[q] = (short)f2bf(v[q]);
      *(s16x4*)(xt + swz(r, 256 + cb*8)) = p;
    }
  }
  // ---- stage h-half (cols 0..127): gather hb[src]+hb[dst], 8 thr/row, 32B each ----
  {
    const int r = tid>>3, jj = tid&7;
    const int ei = base + r;
    int s_ = src[ei], d_ = dstv[ei];
    const s16x8* hs = (const s16x8*)(hb + (size_t)s_*DD) + jj*2;
    const s16x8* hd = (const s16x8*)(hb + (size_t)d_*DD) + jj*2;
    s16x8 a0=hs[0], a1=hs[1], c0=hd[0], c1=hd[1];
    s16x8 o0, o1;
    #pragma unroll
    for (int q=0;q<8;q++){
      o0[q] = (short)f2bf(bf2f((unsigned short)a0[q]) + bf2f((unsigned short)c0[q]));
      o1[q] = (short)f2bf(bf2f((unsigned short)a1[q]) + bf2f((unsigned short)c1[q]));
    }
    *(s16x8*)(xt + swz(r, jj*32))      = o0;
    *(s16x8*)(xt + swz(r, jj*32 + 16)) = o1;
  }
  // ---- B-frags into regs AFTER staging temps die (spill-safety: never overlap) ----
  s16x8 Bf[8][2];
  #pragma unroll
  for (int kc=0;kc<8;kc++)
    #pragma unroll
    for (int nt=0;nt<2;nt++)
      Bf[kc][nt] = *(const s16x8*)(WT1 + (size_t)(nb + nt*16 + lr)*256 + kc*32 + lg*8);
  float bias0 = b1[nb+lr], bias1 = b1[nb+16+lr];
  __syncthreads();
  gemm1_core(xt, Bf, bias0, bias1, yout, stats, base, E);
}

// ======== node gather: CSR sum -> dense x_node bf16 [N,256]; lean regs, (256,8), prefetch ========
__global__ __launch_bounds__(256, 8) void node_gather(
    const unsigned short* __restrict__ hb, const float* __restrict__ enew,
    const int* __restrict__ offsets, const int* __restrict__ eids, const int* __restrict__ esrc,
    unsigned short* __restrict__ xnode, int NN)
{
  const int tid = threadIdx.x;
  const int r = tid>>3, jj = tid&7;
  const int node = blockIdx.x*32 + r;
  if (node >= NN) return;
  float ah[16], ae[16];
  #pragma unroll
  for (int q=0;q<16;q++){ ah[q]=0.f; ae[q]=0.f; }
  int beg = offsets[node], end = offsets[node+1];
  if (beg < end){
    int eid = eids[beg];
    int s_  = esrc[beg];
    for (int p = beg; p < end; p++){
      // prefetch next indices (linear, lane-broadcast) under current row loads
      int pn = (p+1 < end) ? p+1 : p;
      int eid_n = eids[pn];
      int s_n   = esrc[pn];
      const s16x8* hs = (const s16x8*)(hb + (size_t)s_*DD + jj*16);
      const f32x4* ep = (const f32x4*)(enew + (size_t)eid*DD + jj*16);
      s16x8 a0 = hs[0], a1 = hs[1];
      f32x4 e0 = ep[0], e1 = ep[1], e2 = ep[2], e3 = ep[3];
      #pragma unroll
      for (int q=0;q<8;q++){ ah[q] += bf2f((unsigned short)a0[q]); ah[8+q] += bf2f((unsigned short)a1[q]); }
      #pragma unroll
      for (int q=0;q<4;q++){ ae[q] += e0[q]; ae[4+q] += e1[q]; ae[8+q] += e2[q]; ae[12+q] += e3[q]; }
      eid = eid_n; s_ = s_n;
    }
  }
  s16x8 o0, o1;
  #pragma unroll
  for (int q=0;q<8;q++){ o0[q] = (short)f2bf(ah[q]); o1[q] = (short)f2bf(ah[8+q]); }
  *(s16x8*)(xnode + (size_t)node*HH + jj*16)     = o0;
  *(s16x8*)(xnode + (size_t)node*HH + jj*16 + 8) = o1;
  #pragma unroll
  for (int q=0;q<8;q++){ o0[q] = (short)f2bf(ae[q]); o1[q] = (short)f2bf(ae[8+q]); }
  *(s16x8*)(xnode + (size_t)node*HH + 128 + jj*16)     = o0;
  *(s16x8*)(xnode + (size_t)node*HH + 128 + jj*16 + 8) = o1;
}

// ====== node GEMM1: dense x_node tile -> GEMM1 -> ya, stats (one 64-row tile/block; R9-proven) ======
__global__ __launch_bounds__(512, 4) void node_gemm1(
    const unsigned short* __restrict__ xnode,
    const unsigned short* __restrict__ WT1, const float* __restrict__ b1,
    unsigned short* __restrict__ yout, float* __restrict__ stats, int NN)
{
  __shared__ alignas(16) char xt[32768];
  const int tid = threadIdx.x;
  const int l = tid&63, w = tid>>6, lr = l&15, lg = l>>4;
  const int nb = w*32;
  const int base = blockIdx.x*64;

  #pragma unroll
  for (int it=0;it<4;it++){
    int off = it*8192 + tid*16;
    int row = off >> 9, kb = off & 511;
    s16x8 v = {0,0,0,0,0,0,0,0};
    if (base + row < NN) v = *(const s16x8*)((const char*)xnode + (size_t)base*512 + off);
    *(s16x8*)(xt + swz(row, kb)) = v;
  }
  s16x8 Bf[8][2];
  #pragma unroll
  for (int kc=0;kc<8;kc++)
    #pragma unroll
    for (int nt=0;nt<2;nt++)
      Bf[kc][nt] = *(const s16x8*)(WT1 + (size_t)(nb + nt*16 + lr)*256 + kc*32 + lg*8);
  float bias0 = b1[nb+lr], bias1 = b1[nb+16+lr];
  __syncthreads();
  gemm1_core(xt, Bf, bias0, bias1, yout, stats, base, NN);
}

// ---------------- BN finalize ----------------
__global__ void finalize_kernel(const float* __restrict__ stats, const float* __restrict__ g,
                                const float* __restrict__ beta, float* __restrict__ scale, float invcnt){
  __shared__ float red[512];
  int tid = threadIdx.x;
  float s = 0.f;
  for (int rep=0; rep<64; rep++) s += stats[rep*512 + tid];
  red[tid] = s;
  __syncthreads();
  if (tid < 256){
    float mu  = red[tid]*invcnt;
    float var = red[256+tid]*invcnt - mu*mu;
    float a = g[tid] * rsqrtf(var + EPSBN);
    float c = beta[tid] - mu*a;
    scale[2*tid] = a; scale[2*tid+1] = c;
  }
}

// ================= MLP stage 2: 512 thr, TWO 64-row subtiles per block (R10-proven) =================
__global__ __launch_bounds__(512, 4) void mlp2_kernel(const unsigned short* y,
    const unsigned short* __restrict__ WT2, const float* __restrict__ b2,
    const float* __restrict__ scale, float* outp, int nrows)
{
  __shared__ alignas(16) char xt[32768];
  const int tid = threadIdx.x;
  const int l = tid&63, w = tid>>6, lr = l&15, lg = l>>4;
  const int nb = w*16;
  const int base0 = blockIdx.x*128;

  s16x8 Bf[8];
  #pragma unroll
  for (int kc=0;kc<8;kc++)
    Bf[kc] = *(const s16x8*)(WT2 + (size_t)(nb + lr)*HH + kc*32 + lg*8);
  float bias = b2[nb+lr];
  const int cb = tid&31, r0 = tid>>5;
  float sa[8], sc[8];
  #pragma unroll
  for (int q=0;q<8;q++){ sa[q]=scale[2*(cb*8+q)]; sc[q]=scale[2*(cb*8+q)+1]; }

  #pragma unroll 1
  for (int t=0;t<2;t++){
    const int base = base0 + t*64;
    #pragma unroll
    for (int k=0;k<4;k++){
      int r = r0 + k*16;
      s16x8 raw = {0,0,0,0,0,0,0,0};
      if (base + r < nrows) raw = *(const s16x8*)(y + (size_t)(base+r)*HH + cb*8);
      s16x8 o;
      #pragma unroll
      for (int q=0;q<8;q++){
        float f = fmaxf(bf2f((unsigned short)raw[q])*sa[q] + sc[q], 0.0f);
        o[q] = (short)f2bf(f);
      }
      *(s16x8*)(xt + swz(r, cb*16)) = o;
    }
    __syncthreads();
    f32x4 acc[4];
    #pragma unroll
    for (int mt=0;mt<4;mt++) acc[mt] = (f32x4){0.f,0.f,0.f,0.f};
    #pragma unroll
    for (int kc=0;kc<8;kc++){
      s16x8 af[4];
      #pragma unroll
      for (int mt=0;mt<4;mt++)
        af[mt] = *(const s16x8*)(xt + swz(mt*16 + lr, kc*64 + lg*16));
      #pragma unroll
      for (int mt=0;mt<4;mt++)
        acc[mt] = __builtin_amdgcn_mfma_f32_16x16x32_bf16(af[mt], Bf[kc], acc[mt], 0,0,0);
    }
    __syncthreads();
    #pragma unroll
    for (int mt=0;mt<4;mt++)
      #pragma unroll
      for (int q=0;q<4;q++)
        *(float*)(xt + (mt*16 + lg*4 + q)*512 + (nb + lr)*4) = acc[mt][q] + bias;
    __syncthreads();
    #pragma unroll
    for (int it=0;it<4;it++){
      int off = it*8192 + tid*16;
      int row = off >> 9;
      if (base + row < nrows)
        *(f32x4*)(outp + (size_t)(base+row)*DD + ((off&511)>>2)) = *(const f32x4*)(xt + off);
    }
    if (t==0) __syncthreads();
  }
}

extern "C" void kernel_launch(void* const* d_in, const int* in_sizes, int n_in,
                              void* d_out, int out_size, void* d_ws, size_t ws_size,
                              hipStream_t stream) {
  const float* h    = (const float*)d_in[0];
  const float* e    = (const float*)d_in[1];
  const int*   src  = (const int*)d_in[2];
  const int*   dst  = (const int*)d_in[3];
  const float* W1b  = (const float*)d_in[4];
  const float* b1b  = (const float*)d_in[5];
  const float* g1b  = (const float*)d_in[6];
  const float* beta1b=(const float*)d_in[7];
  const float* W2b  = (const float*)d_in[8];
  const float* b2b  = (const float*)d_in[9];
  const float* W1a  = (const float*)d_in[10];
  const float* b1a  = (const float*)d_in[11];
  const float* g1a  = (const float*)d_in[12];
  const float* beta1a=(const float*)d_in[13];
  const float* W2a  = (const float*)d_in[14];
  const float* b2a  = (const float*)d_in[15];

  const int E  = in_sizes[2];
  const int NN = in_sizes[0] / DD;

  // ws layout (bytes)
  char* ws = (char*)d_ws;
  unsigned short* WT1b = (unsigned short*)(ws + 0);        // 131072
  unsigned short* WT2b = (unsigned short*)(ws + 131072);   // 65536
  unsigned short* WT1a = (unsigned short*)(ws + 196608);   // 131072
  unsigned short* WT2a = (unsigned short*)(ws + 327680);   // 65536
  float* scaleE = (float*)(ws + 393216);                   // 2048
  float* scaleN = (float*)(ws + 395264);                   // 2048
  float* statsE = (float*)(ws + 397312);                   // 131072 (64 reps x 512)
  float* statsN = (float*)(ws + 528384);                   // 131072
  int* counts  = (int*)(ws + 659456);                      // 200704
  int* offsets = (int*)(ws + 860160);                      // 200704
  int* cursor  = (int*)(ws + 1060864);                     // 200704
  int* eids    = (int*)(ws + 1261568);                     // 3200000
  unsigned short* ya = (unsigned short*)(ws + 4461568);    // 50048*256*2 = 25624576
  unsigned short* hb = (unsigned short*)(ws + 30086144);   // NN*128*2 = 12800000
  int* esrc   = (int*)(ws + 42886144);                     // 3200000 (ends 46086144)

  float* outH = (float*)d_out;
  float* outE = outH + (size_t)NN * DD;
  unsigned short* yE = (unsigned short*)outE;      // bf16 y shares bytes with e_new region
  unsigned short* xnode = (unsigned short*)outH;   // dense node input in h_new region
                                                   // (NN*256*2B == NN*128*4B; consumed before mlp2_N)

  // zero statsE + statsN + counts (contiguous)
  hipMemsetAsync(ws + 397312, 0, 131072 + 131072 + 200704, stream);

  wt_kernel<<<768, 256, 0, stream>>>(W1b, W2b, W1a, W2a, WT1b, WT2b, WT1a, WT2a);
  h2bf_hist_kernel<<<(NN*DD/8 + 255)/256, 256, 0, stream>>>(h, hb, NN*DD/8, dst, counts, E);
  scan_kernel<<<1, 1024, 0, stream>>>(counts, offsets, cursor, NN);
  fill_kernel<<<(E+255)/256, 256, 0, stream>>>(dst, src, cursor, eids, esrc, E);

  const int tE64  = E/64;              // E is a multiple of 64
  const int tE128 = E/128;             // and of 128
  const int tN64  = (NN + 63)/64;
  const int tN128 = (NN + 127)/128;
  const int gG    = (NN + 31)/32;

  edge_mlp1<<<tE64, 512, 0, stream>>>(hb, e, src, dst, WT1b, b1b, yE, statsE, E);
  finalize_kernel<<<1, 512, 0, stream>>>(statsE, g1b, beta1b, scaleE, 1.0f/(float)E);
  mlp2_kernel<<<tE128, 512, 0, stream>>>(yE, WT2b, b2b, scaleE, outE, E);   // in-place y -> e_new
  node_gather<<<gG, 256, 0, stream>>>(hb, outE, offsets, eids, esrc, xnode, NN);
  node_gemm1<<<tN64, 512, 0, stream>>>(xnode, WT1a, b1a, ya, statsN, NN);
  finalize_kernel<<<1, 512, 0, stream>>>(statsN, g1a, beta1a, scaleN, 1.0f/(float)NN);
  mlp2_kernel<<<tN128, 512, 0, stream>>>(ya, WT2a, b2a, scaleN, outH, NN);
}

// Round 13
// 775.646 us; speedup vs baseline: 1.0850x; 1.0850x over previous
//
#include <hip/hip_runtime.h>
#include <hip/hip_bf16.h>
#include <stdint.h>

#define DD 128
#define HH 256
#define EPSBN 1e-5f

typedef __attribute__((ext_vector_type(4))) float f32x4;
typedef __attribute__((ext_vector_type(8))) short s16x8;
typedef __attribute__((ext_vector_type(4))) short s16x4;

__device__ __forceinline__ unsigned short f2bf(float f){
  union { __hip_bfloat16 h; unsigned short u; } v;
  v.h = __float2bfloat16(f);
  return v.u;
}
__device__ __forceinline__ float bf2f(unsigned short s){
  union{unsigned u; float f;} v; v.u=((unsigned)s)<<16; return v.f;
}
// XOR swizzle inside a 64-row x 512-byte LDS tile (wide XOR: conflicts 2.08e7 -> ~5e6)
__device__ __forceinline__ int swz(int row, int kb){ return row*512 + (kb ^ ((row&31)<<4)); }

// ---------------- weight transpose (fp32 [k][n] -> bf16 [n][k]) ----------------
__global__ void wt_kernel(const float* __restrict__ W1b, const float* __restrict__ W2b,
                          const float* __restrict__ W1a, const float* __restrict__ W2a,
                          unsigned short* __restrict__ WT1b, unsigned short* __restrict__ WT2b,
                          unsigned short* __restrict__ WT1a, unsigned short* __restrict__ WT2a){
  int idx = blockIdx.x*256 + threadIdx.x;
  if (idx < 65536){ int n=idx>>8, k=idx&255; WT1b[n*256+k]=f2bf(W1b[k*256+n]); }
  else if (idx < 98304){ int t=idx-65536; int n=t>>8, k=t&255; WT2b[n*256+k]=f2bf(W2b[k*128+n]); }
  else if (idx < 163840){ int t=idx-98304; int n=t>>8, k=t&255; WT1a[n*256+k]=f2bf(W1a[k*256+n]); }
  else if (idx < 196608){ int t=idx-163840; int n=t>>8, k=t&255; WT2a[n*256+k]=f2bf(W2a[k*128+n]); }
}

// ---------------- fused: h fp32 -> bf16  +  dst histogram ----------------
__global__ void h2bf_hist_kernel(const float* __restrict__ h, unsigned short* __restrict__ hb, int n8,
                                 const int* __restrict__ dst, int* __restrict__ counts, int E){
  int i = blockIdx.x*256 + threadIdx.x;
  if (i < n8){
    f32x4 a = *(const f32x4*)(h + (size_t)i*8);
    f32x4 b = *(const f32x4*)(h + (size_t)i*8 + 4);
    s16x8 p;
    #pragma unroll
    for (int q=0;q<4;q++){ p[q]=(short)f2bf(a[q]); p[4+q]=(short)f2bf(b[q]); }
    *(s16x8*)(hb + (size_t)i*8) = p;
  }
  if (i < E) atomicAdd(&counts[dst[i]], 1);
}

__global__ void scan_kernel(const int* __restrict__ counts, int* __restrict__ offsets,
                            int* __restrict__ cursor, int n){
  __shared__ int wsum[16];
  int tid = threadIdx.x, lane = tid&63, wid = tid>>6;
  int carry = 0;
  int nch = (n + 1023)/1024;
  for (int ch=0; ch<nch; ch++){
    int i = ch*1024 + tid;
    int v = (i<n)? counts[i] : 0;
    int s = v;
    #pragma unroll
    for (int off=1; off<64; off<<=1){ int t = __shfl_up(s, off); if (lane>=off) s += t; }
    if (lane==63) wsum[wid] = s;
    __syncthreads();
    int woff = 0, tot = 0;
    #pragma unroll
    for (int w=0; w<16; w++){ int t = wsum[w]; if (w<wid) woff += t; tot += t; }
    if (i<n){ int excl = carry + woff + s - v; offsets[i]=excl; cursor[i]=excl; }
    carry += tot;
    __syncthreads();
  }
  if (tid==0) offsets[n] = carry;
}

// fill also dereferences src[i] once so the node gather loop has NO src[eid] chase
__global__ void fill_kernel(const int* __restrict__ dst, const int* __restrict__ srcv,
                            int* __restrict__ cursor,
                            int* __restrict__ eids, int* __restrict__ esrc, int E){
  int i = blockIdx.x*256 + threadIdx.x;
  if (i < E){
    int slot = atomicAdd(&cursor[dst[i]], 1);
    eids[slot] = i;
    esrc[slot] = srcv[i];
  }
}

// ===== shared 512-thr GEMM1 core: x[64x256](LDS) @ WT[256x256](regs) + b, BN stats, y bf16 out =====
__device__ __forceinline__ void gemm1_core(char* xt, const s16x8 (&Bf)[8][2],
                                           float bias0, float bias1,
                                           unsigned short* __restrict__ yout,
                                           float* __restrict__ stats,
                                           int base, int nrows)
{
  const int tid = threadIdx.x;
  const int l = tid&63, w = tid>>6, lr = l&15, lg = l>>4;
  const int nb = w*32;
  f32x4 acc[4][2];
  #pragma unroll
  for (int mt=0;mt<4;mt++)
    #pragma unroll
    for (int nt=0;nt<2;nt++) acc[mt][nt] = (f32x4){0.f,0.f,0.f,0.f};
  #pragma unroll
  for (int kc=0;kc<8;kc++){
    s16x8 af[4];
    #pragma unroll
    for (int mt=0;mt<4;mt++)
      af[mt] = *(const s16x8*)(xt + swz(mt*16 + lr, kc*64 + lg*16));
    #pragma unroll
    for (int nt=0;nt<2;nt++)
      #pragma unroll
      for (int mt=0;mt<4;mt++)
        acc[mt][nt] = __builtin_amdgcn_mfma_f32_16x16x32_bf16(af[mt], Bf[kc][nt], acc[mt][nt], 0,0,0);
  }
  float st1a=0.f, st1b=0.f, st2a=0.f, st2b=0.f;
  #pragma unroll
  for (int mt=0;mt<4;mt++)
    #pragma unroll
    for (int q=0;q<4;q++){
      float m = (base + mt*16 + lg*4 + q < nrows) ? 1.0f : 0.0f;
      float v0 = (acc[mt][0][q] + bias0)*m;
      float v1 = (acc[mt][1][q] + bias1)*m;
      st1a += v0; st2a += v0*v0;
      st1b += v1; st2b += v1*v1;
    }
  __syncthreads();
  #pragma unroll
  for (int mt=0;mt<4;mt++)
    #pragma unroll
    for (int q=0;q<4;q++){
      *(unsigned short*)(xt + (mt*16 + lg*4 + q)*512 + (nb + lr)*2)      = f2bf(acc[mt][0][q] + bias0);
      *(unsigned short*)(xt + (mt*16 + lg*4 + q)*512 + (nb + 16 + lr)*2) = f2bf(acc[mt][1][q] + bias1);
    }
  __syncthreads();
  #pragma unroll
  for (int it=0;it<4;it++){
    int off = it*8192 + tid*16;
    int row = off >> 9;
    if (base + row < nrows)
      *(s16x8*)((char*)yout + (size_t)base*512 + off) = *(const s16x8*)(xt + off);
  }
  {
    int rep = blockIdx.x & 63;
    float s;
    s = st1a; s += __shfl_xor(s,16); s += __shfl_xor(s,32);
    if (l < 16) atomicAdd(&stats[rep*512 + nb + lr], s);
    s = st2a; s += __shfl_xor(s,16); s += __shfl_xor(s,32);
    if (l < 16) atomicAdd(&stats[rep*512 + 256 + nb + lr], s);
    s = st1b; s += __shfl_xor(s,16); s += __shfl_xor(s,32);
    if (l < 16) atomicAdd(&stats[rep*512 + nb + 16 + lr], s);
    s = st2b; s += __shfl_xor(s,16); s += __shfl_xor(s,32);
    if (l < 16) atomicAdd(&stats[rep*512 + 256 + nb + 16 + lr], s);
  }
}

// ================= edge MLP stage 1: one 64-row tile per block, issue-early gather =================
__global__ __launch_bounds__(512, 4) void edge_mlp1(
    const unsigned short* __restrict__ hb, const float* __restrict__ e,
    const int* __restrict__ src, const int* __restrict__ dstv,
    const unsigned short* __restrict__ WT1, const float* __restrict__ b1,
    unsigned short* __restrict__ yout, float* __restrict__ stats, int E)
{
  __shared__ alignas(16) char xt[32768];
  const int tid = threadIdx.x;
  const int l = tid&63, w = tid>>6, lr = l&15, lg = l>>4;
  const int nb = w*32;
  const int base = blockIdx.x*64;   // E multiple of 64 -> no row guards

  // ---- issue ALL loads first: src/dst, e-rows, then gather rows (vmcnt retires in order,
  //      so e-processing below waits only on e loads while gather stays in flight) ----
  const int r = tid>>3, jj = tid&7;
  const int ei = base + r;
  int s_ = src[ei], d_ = dstv[ei];

  const int cb = tid&31, r0 = tid>>5;
  f32x4 ev[4];
  #pragma unroll
  for (int k=0;k<4;k++)
    ev[k] = *(const f32x4*)(e + (size_t)(base + r0 + k*16)*DD + cb*4);

  const s16x8* hs = (const s16x8*)(hb + (size_t)s_*DD) + jj*2;
  const s16x8* hd = (const s16x8*)(hb + (size_t)d_*DD) + jj*2;
  s16x8 a0=hs[0], a1=hs[1], c0=hd[0], c1=hd[1];

  // ---- process e (cvt + LDS) while gather loads are in flight ----
  #pragma unroll
  for (int k=0;k<4;k++){
    s16x4 p;
    #pragma unroll
    for (int q=0;q<4;q++) p[q] = (short)f2bf(ev[k][q]);
    *(s16x4*)(xt + swz(r0 + k*16, 256 + cb*8)) = p;
  }
  // ---- process gather ----
  {
    s16x8 o0, o1;
    #pragma unroll
    for (int q=0;q<8;q++){
      o0[q] = (short)f2bf(bf2f((unsigned short)a0[q]) + bf2f((unsigned short)c0[q]));
      o1[q] = (short)f2bf(bf2f((unsigned short)a1[q]) + bf2f((unsigned short)c1[q]));
    }
    *(s16x8*)(xt + swz(r, jj*32))      = o0;
    *(s16x8*)(xt + swz(r, jj*32 + 16)) = o1;
  }
  // ---- B-frags into regs AFTER staging temps die (spill-safety: never overlap) ----
  s16x8 Bf[8][2];
  #pragma unroll
  for (int kc=0;kc<8;kc++)
    #pragma unroll
    for (int nt=0;nt<2;nt++)
      Bf[kc][nt] = *(const s16x8*)(WT1 + (size_t)(nb + nt*16 + lr)*256 + kc*32 + lg*8);
  float bias0 = b1[nb+lr], bias1 = b1[nb+16+lr];
  __syncthreads();
  gemm1_core(xt, Bf, bias0, bias1, yout, stats, base, E);
}

// ====== node MLP stage 1: fused CSR gather (esrc de-chase + prefetch) -> GEMM1 ======
__global__ __launch_bounds__(512, 4) void node_mlp1(
    const unsigned short* __restrict__ hb, const float* __restrict__ enew,
    const int* __restrict__ offsets, const int* __restrict__ eids, const int* __restrict__ esrc,
    const unsigned short* __restrict__ WT1, const float* __restrict__ b1,
    unsigned short* __restrict__ yout, float* __restrict__ stats, int NN)
{
  __shared__ alignas(16) char xt[32768];
  const int tid = threadIdx.x;
  const int l = tid&63, w = tid>>6, lr = l&15, lg = l>>4;
  const int nb = w*32;
  const int base = blockIdx.x*64;
  const int r = tid>>3, jj = tid&7;
  const int node = base + r;

  float ah[16], ae[16];
  #pragma unroll
  for (int q=0;q<16;q++){ ah[q]=0.f; ae[q]=0.f; }
  if (node < NN){
    int beg = offsets[node], end = offsets[node+1];
    if (beg < end){
      int eid = eids[beg];
      int s_  = esrc[beg];
      for (int p = beg; p < end; p++){
        int pn = (p+1 < end) ? p+1 : p;
        int eid_n = eids[pn];          // linear loads, prefetch under row loads
        int s_n   = esrc[pn];
        const s16x8* hsp = (const s16x8*)(hb + (size_t)s_*DD + jj*16);
        const f32x4* ep = (const f32x4*)(enew + (size_t)eid*DD + jj*16);
        s16x8 a0 = hsp[0], a1 = hsp[1];
        f32x4 e0 = ep[0], e1 = ep[1], e2 = ep[2], e3 = ep[3];
        #pragma unroll
        for (int q=0;q<8;q++){ ah[q] += bf2f((unsigned short)a0[q]); ah[8+q] += bf2f((unsigned short)a1[q]); }
        #pragma unroll
        for (int q=0;q<4;q++){ ae[q] += e0[q]; ae[4+q] += e1[q]; ae[8+q] += e2[q]; ae[12+q] += e3[q]; }
        eid = eid_n; s_ = s_n;
      }
    }
  }
  {
    s16x8 o0, o1;
    #pragma unroll
    for (int q=0;q<8;q++){ o0[q] = (short)f2bf(ah[q]); o1[q] = (short)f2bf(ah[8+q]); }
    *(s16x8*)(xt + swz(r, jj*32))      = o0;
    *(s16x8*)(xt + swz(r, jj*32 + 16)) = o1;
    #pragma unroll
    for (int q=0;q<8;q++){ o0[q] = (short)f2bf(ae[q]); o1[q] = (short)f2bf(ae[8+q]); }
    *(s16x8*)(xt + swz(r, 256 + jj*32))      = o0;
    *(s16x8*)(xt + swz(r, 256 + jj*32 + 16)) = o1;
  }
  s16x8 Bf[8][2];
  #pragma unroll
  for (int kc=0;kc<8;kc++)
    #pragma unroll
    for (int nt=0;nt<2;nt++)
      Bf[kc][nt] = *(const s16x8*)(WT1 + (size_t)(nb + nt*16 + lr)*256 + kc*32 + lg*8);
  float bias0 = b1[nb+lr], bias1 = b1[nb+16+lr];
  __syncthreads();
  gemm1_core(xt, Bf, bias0, bias1, yout, stats, base, NN);
}

// ---------------- BN finalize ----------------
__global__ void finalize_kernel(const float* __restrict__ stats, const float* __restrict__ g,
                                const float* __restrict__ beta, float* __restrict__ scale, float invcnt){
  __shared__ float red[512];
  int tid = threadIdx.x;
  float s = 0.f;
  for (int rep=0; rep<64; rep++) s += stats[rep*512 + tid];
  red[tid] = s;
  __syncthreads();
  if (tid < 256){
    float mu  = red[tid]*invcnt;
    float var = red[256+tid]*invcnt - mu*mu;
    float a = g[tid] * rsqrtf(var + EPSBN);
    float c = beta[tid] - mu*a;
    scale[2*tid] = a; scale[2*tid+1] = c;
  }
}

// ================= MLP stage 2: 512 thr, TWO 64-row subtiles per block (R10-proven) =================
__global__ __launch_bounds__(512, 4) void mlp2_kernel(const unsigned short* y,
    const unsigned short* __restrict__ WT2, const float* __restrict__ b2,
    const float* __restrict__ scale, float* outp, int nrows)
{
  __shared__ alignas(16) char xt[32768];
  const int tid = threadIdx.x;
  const int l = tid&63, w = tid>>6, lr = l&15, lg = l>>4;
  const int nb = w*16;
  const int base0 = blockIdx.x*128;

  s16x8 Bf[8];
  #pragma unroll
  for (int kc=0;kc<8;kc++)
    Bf[kc] = *(const s16x8*)(WT2 + (size_t)(nb + lr)*HH + kc*32 + lg*8);
  float bias = b2[nb+lr];
  const int cb = tid&31, r0 = tid>>5;
  float sa[8], sc[8];
  #pragma unroll
  for (int q=0;q<8;q++){ sa[q]=scale[2*(cb*8+q)]; sc[q]=scale[2*(cb*8+q)+1]; }

  #pragma unroll 1
  for (int t=0;t<2;t++){
    const int base = base0 + t*64;
    #pragma unroll
    for (int k=0;k<4;k++){
      int r = r0 + k*16;
      s16x8 raw = {0,0,0,0,0,0,0,0};
      if (base + r < nrows) raw = *(const s16x8*)(y + (size_t)(base+r)*HH + cb*8);
      s16x8 o;
      #pragma unroll
      for (int q=0;q<8;q++){
        float f = fmaxf(bf2f((unsigned short)raw[q])*sa[q] + sc[q], 0.0f);
        o[q] = (short)f2bf(f);
      }
      *(s16x8*)(xt + swz(r, cb*16)) = o;
    }
    __syncthreads();
    f32x4 acc[4];
    #pragma unroll
    for (int mt=0;mt<4;mt++) acc[mt] = (f32x4){0.f,0.f,0.f,0.f};
    #pragma unroll
    for (int kc=0;kc<8;kc++){
      s16x8 af[4];
      #pragma unroll
      for (int mt=0;mt<4;mt++)
        af[mt] = *(const s16x8*)(xt + swz(mt*16 + lr, kc*64 + lg*16));
      #pragma unroll
      for (int mt=0;mt<4;mt++)
        acc[mt] = __builtin_amdgcn_mfma_f32_16x16x32_bf16(af[mt], Bf[kc], acc[mt], 0,0,0);
    }
    __syncthreads();
    #pragma unroll
    for (int mt=0;mt<4;mt++)
      #pragma unroll
      for (int q=0;q<4;q++)
        *(float*)(xt + (mt*16 + lg*4 + q)*512 + (nb + lr)*4) = acc[mt][q] + bias;
    __syncthreads();
    #pragma unroll
    for (int it=0;it<4;it++){
      int off = it*8192 + tid*16;
      int row = off >> 9;
      if (base + row < nrows)
        *(f32x4*)(outp + (size_t)(base+row)*DD + ((off&511)>>2)) = *(const f32x4*)(xt + off);
    }
    if (t==0) __syncthreads();
  }
}

extern "C" void kernel_launch(void* const* d_in, const int* in_sizes, int n_in,
                              void* d_out, int out_size, void* d_ws, size_t ws_size,
                              hipStream_t stream) {
  const float* h    = (const float*)d_in[0];
  const float* e    = (const float*)d_in[1];
  const int*   src  = (const int*)d_in[2];
  const int*   dst  = (const int*)d_in[3];
  const float* W1b  = (const float*)d_in[4];
  const float* b1b  = (const float*)d_in[5];
  const float* g1b  = (const float*)d_in[6];
  const float* beta1b=(const float*)d_in[7];
  const float* W2b  = (const float*)d_in[8];
  const float* b2b  = (const float*)d_in[9];
  const float* W1a  = (const float*)d_in[10];
  const float* b1a  = (const float*)d_in[11];
  const float* g1a  = (const float*)d_in[12];
  const float* beta1a=(const float*)d_in[13];
  const float* W2a  = (const float*)d_in[14];
  const float* b2a  = (const float*)d_in[15];

  const int E  = in_sizes[2];
  const int NN = in_sizes[0] / DD;

  // ws layout (bytes)
  char* ws = (char*)d_ws;
  unsigned short* WT1b = (unsigned short*)(ws + 0);        // 131072
  unsigned short* WT2b = (unsigned short*)(ws + 131072);   // 65536
  unsigned short* WT1a = (unsigned short*)(ws + 196608);   // 131072
  unsigned short* WT2a = (unsigned short*)(ws + 327680);   // 65536
  float* scaleE = (float*)(ws + 393216);                   // 2048
  float* scaleN = (float*)(ws + 395264);                   // 2048
  float* statsE = (float*)(ws + 397312);                   // 131072 (64 reps x 512)
  float* statsN = (float*)(ws + 528384);                   // 131072
  int* counts  = (int*)(ws + 659456);                      // 200704
  int* offsets = (int*)(ws + 860160);                      // 200704
  int* cursor  = (int*)(ws + 1060864);                     // 200704
  int* eids    = (int*)(ws + 1261568);                     // 3200000
  unsigned short* ya = (unsigned short*)(ws + 4461568);    // 50048*256*2 = 25624576
  unsigned short* hb = (unsigned short*)(ws + 30086144);   // NN*128*2 = 12800000
  int* esrc   = (int*)(ws + 42886144);                     // 3200000 (ends 46086144)

  float* outH = (float*)d_out;
  float* outE = outH + (size_t)NN * DD;
  unsigned short* yE = (unsigned short*)outE;   // bf16 y shares bytes with e_new region

  // zero statsE + statsN + counts (contiguous)
  hipMemsetAsync(ws + 397312, 0, 131072 + 131072 + 200704, stream);

  wt_kernel<<<768, 256, 0, stream>>>(W1b, W2b, W1a, W2a, WT1b, WT2b, WT1a, WT2a);
  h2bf_hist_kernel<<<(NN*DD/8 + 255)/256, 256, 0, stream>>>(h, hb, NN*DD/8, dst, counts, E);
  scan_kernel<<<1, 1024, 0, stream>>>(counts, offsets, cursor, NN);
  fill_kernel<<<(E+255)/256, 256, 0, stream>>>(dst, src, cursor, eids, esrc, E);

  const int tE64  = E/64;              // E is a multiple of 64
  const int tE128 = E/128;             // and of 128
  const int tN64  = (NN + 63)/64;
  const int tN128 = (NN + 127)/128;

  edge_mlp1<<<tE64, 512, 0, stream>>>(hb, e, src, dst, WT1b, b1b, yE, statsE, E);
  finalize_kernel<<<1, 512, 0, stream>>>(statsE, g1b, beta1b, scaleE, 1.0f/(float)E);
  mlp2_kernel<<<tE128, 512, 0, stream>>>(yE, WT2b, b2b, scaleE, outE, E);   // in-place y -> e_new
  node_mlp1<<<tN64, 512, 0, stream>>>(hb, outE, offsets, eids, esrc, WT1a, b1a, ya, statsN, NN);
  finalize_kernel<<<1, 512, 0, stream>>>(statsN, g1a, beta1a, scaleN, 1.0f/(float)NN);
  mlp2_kernel<<<tN128, 512, 0, stream>>>(ya, WT2a, b2a, scaleN, outH, NN);
}